// Round 1
// baseline (575.985 us; speedup 1.0000x reference)
//
#include <hip/hip_runtime.h>

#define N_IMG 256
#define N_ANG 256
#define N_BATCH 8
#define CENTER 127.5f

// Pair texture: P[b][r][x] = (im[r-1][x] or 0, im[r][x] or 0), r in [0,256].
// A bilinear sample at (row R, col C) with r0=floor(R), c0=floor(C) needs
// P[r0+1][c0] and P[r0+1][c0+1]: two 8B loads instead of four 4B loads,
// with row-OOB handled by the zero-padded border rows of the texture.
__global__ __launch_bounds__(256) void radon_prep(const float* __restrict__ x,
                                                  float2* __restrict__ P,
                                                  float2* __restrict__ PT) {
    int b = blockIdx.x / 257;
    int r = blockIdx.x - b * 257;
    int col = threadIdx.x;
    const float* im = x + (size_t)b * (N_IMG * N_IMG);

    float top = (r >= 1)         ? im[(r - 1) * N_IMG + col] : 0.0f;
    float bot = (r <= N_IMG - 1) ? im[r * N_IMG + col]       : 0.0f;
    P[((size_t)b * 257 + r) * N_IMG + col] = make_float2(top, bot);

    // transposed image pair texture (for steep angles)
    float topT = (r >= 1)         ? im[col * N_IMG + (r - 1)] : 0.0f;
    float botT = (r <= N_IMG - 1) ? im[col * N_IMG + r]       : 0.0f;
    PT[((size_t)b * 257 + r) * N_IMG + col] = make_float2(topT, botT);
}

__global__ __launch_bounds__(256) void radon_fwd(const float* __restrict__ angles,
                                                 const float2* __restrict__ P,
                                                 const float2* __restrict__ PT,
                                                 float* __restrict__ out) {
    int a = blockIdx.x % N_ANG;
    int b = blockIdx.x / N_ANG;
    int d = threadIdx.x;

    float ang = angles[a];
    float cs = cosf(ang), sn = sinf(ang);
    bool swapped = fabsf(sn) > fabsf(cs);   // block-uniform

    float td = (float)d - CENTER;
    // Reference: X = t*cos - s*sin + c ; Y = t*sin + s*cos + c
    // Row/col coordinate for the (possibly transposed) texture:
    float Rbase, Cbase, dR, dC;
    if (!swapped) {
        Rbase = td * sn + CENTER;  dR = cs;    // row  = Y
        Cbase = td * cs + CENTER;  dC = -sn;   // col  = X
    } else {
        Rbase = td * cs + CENTER;  dR = -sn;   // row  = X (transposed image)
        Cbase = td * sn + CENTER;  dC = cs;    // col  = Y
    }
    const float2* tex = (swapped ? PT : P) + (size_t)b * (257 * N_IMG);

    float acc = 0.0f;
    #pragma unroll 4
    for (int si = 0; si < N_IMG; ++si) {
        float sf = (float)si - CENTER;
        float R = fmaf(sf, dR, Rbase);
        float C = fmaf(sf, dC, Cbase);
        float fr = floorf(R), fc = floorf(C);
        int r0 = (int)fr, c0 = (int)fc;
        float wr = R - fr, wc = C - fc;
        // sample contributes iff r0 in [-1,255] and c0 in [-1,255]
        if ((unsigned)(r0 + 1) <= 256u && (unsigned)(c0 + 1) <= 256u) {
            const float2* rowp = tex + (size_t)(r0 + 1) * N_IMG;
            float2 v0 = ((unsigned)c0 < (unsigned)N_IMG) ? rowp[c0]
                                                         : make_float2(0.0f, 0.0f);
            float2 v1 = ((unsigned)(c0 + 1) < (unsigned)N_IMG) ? rowp[c0 + 1]
                                                               : make_float2(0.0f, 0.0f);
            float a0 = fmaf(wr, v0.y - v0.x, v0.x);   // lerp rows @ col c0
            float a1 = fmaf(wr, v1.y - v1.x, v1.x);   // lerp rows @ col c0+1
            acc += fmaf(wc, a1 - a0, a0);             // lerp cols
        }
    }
    out[((size_t)b * N_ANG + a) * N_IMG + d] = acc;
}

// Fallback (workspace too small): direct 4-load bilinear from the raw image.
__global__ __launch_bounds__(256) void radon_fwd_basic(const float* __restrict__ x,
                                                       const float* __restrict__ angles,
                                                       float* __restrict__ out) {
    int a = blockIdx.x % N_ANG;
    int b = blockIdx.x / N_ANG;
    int d = threadIdx.x;

    float ang = angles[a];
    float cs = cosf(ang), sn = sinf(ang);
    float td = (float)d - CENTER;
    float Xb = td * cs + CENTER;
    float Yb = td * sn + CENTER;
    const float* im = x + (size_t)b * (N_IMG * N_IMG);

    float acc = 0.0f;
    for (int si = 0; si < N_IMG; ++si) {
        float sf = (float)si - CENTER;
        float X = fmaf(sf, -sn, Xb);
        float Y = fmaf(sf, cs, Yb);
        float fx = floorf(X), fy = floorf(Y);
        int x0 = (int)fx, y0 = (int)fy;
        float wx = X - fx, wy = Y - fy;
        bool ry0 = (unsigned)y0 < (unsigned)N_IMG;
        bool ry1 = (unsigned)(y0 + 1) < (unsigned)N_IMG;
        bool cx0 = (unsigned)x0 < (unsigned)N_IMG;
        bool cx1 = (unsigned)(x0 + 1) < (unsigned)N_IMG;
        float v00 = (ry0 && cx0) ? im[y0 * N_IMG + x0]           : 0.0f;
        float v01 = (ry0 && cx1) ? im[y0 * N_IMG + x0 + 1]       : 0.0f;
        float v10 = (ry1 && cx0) ? im[(y0 + 1) * N_IMG + x0]     : 0.0f;
        float v11 = (ry1 && cx1) ? im[(y0 + 1) * N_IMG + x0 + 1] : 0.0f;
        float a0 = fmaf(wy, v10 - v00, v00);
        float a1 = fmaf(wy, v11 - v01, v01);
        acc += fmaf(wx, a1 - a0, a0);
    }
    out[((size_t)b * N_ANG + a) * N_IMG + d] = acc;
}

extern "C" void kernel_launch(void* const* d_in, const int* in_sizes, int n_in,
                              void* d_out, int out_size, void* d_ws, size_t ws_size,
                              hipStream_t stream) {
    const float* x      = (const float*)d_in[0];
    const float* angles = (const float*)d_in[1];
    float* out = (float*)d_out;

    const size_t texElems = (size_t)N_BATCH * 257 * N_IMG;   // float2 elements
    const size_t need = 2 * texElems * sizeof(float2);       // P + PT ~ 8.03 MB

    if (ws_size >= need) {
        float2* P  = (float2*)d_ws;
        float2* PT = P + texElems;
        radon_prep<<<N_BATCH * 257, 256, 0, stream>>>(x, P, PT);
        radon_fwd<<<N_BATCH * N_ANG, 256, 0, stream>>>(angles, P, PT, out);
    } else {
        radon_fwd_basic<<<N_BATCH * N_ANG, 256, 0, stream>>>(x, angles, out);
    }
}

// Round 2
// 478.929 us; speedup vs baseline: 1.2027x; 1.2027x over previous
//
#include <hip/hip_runtime.h>
#include <hip/hip_fp16.h>

#define N_IMG 256
#define N_ANG 256
#define N_BATCH 8
#define CENTER 127.5f
#define PADW 258                      // cols -1..256
#define PADH 259                      // rows -1..256 + one extra zero row (dump)
#define LDS_HALFS (PADH * PADW)       // 66,822 halves = 133,644 B

// One block = one batch image staged to LDS (fp16, zero-padded) + 4 angles.
// Bilinear taps are 4x ds_read_u16 with immediate offsets 0/2/516/518 off a
// single per-lane vaddr; row stride 516B = 129 dwords (odd) spreads banks at
// every angle. OOB samples redirect to a zeroed dump row (row 257/258, col 0/1).
__global__ __launch_bounds__(1024) void radon_lds(const float* __restrict__ x,
                                                  const float* __restrict__ angles,
                                                  float* __restrict__ out) {
    __shared__ __half S[LDS_HALFS];

    int b    = blockIdx.x & 7;        // batch = blockIdx % 8 -> XCD-resident image
    int agrp = blockIdx.x >> 3;       // 0..63, 4 angles each
    int tid  = threadIdx.x;

    // zero all of LDS (dword-wide; LDS_HALFS is even)
    uint32_t* S32 = (uint32_t*)S;
    for (int i = tid; i < LDS_HALFS / 2; i += 1024) S32[i] = 0u;
    __syncthreads();

    // stage image b: S[(r+1)*PADW + (c+1)] = fp16(im[r][c]); float4-coalesced reads
    const float* im = x + (size_t)b * (N_IMG * N_IMG);
    for (int i = tid; i < (N_IMG * N_IMG) / 4; i += 1024) {
        float4 v = ((const float4*)im)[i];
        int p = i * 4;
        int r = p >> 8, c = p & 255;
        __half* dst = &S[(r + 1) * PADW + (c + 1)];
        dst[0] = __float2half(v.x);
        dst[1] = __float2half(v.y);
        dst[2] = __float2half(v.z);
        dst[3] = __float2half(v.w);
    }
    __syncthreads();

    int d = tid & 255;                // detector
    int a = agrp * 4 + (tid >> 8);    // angle
    float ang = angles[a];
    float sn = sinf(ang), cs = cosf(ang);
    float td = (float)d - CENTER;
    // Reference: X = t*cos - s*sin + c (col), Y = t*sin + s*cos + c (row)
    float Xb = fmaf(td, cs, CENTER);
    float Yb = fmaf(td, sn, CENTER);

    float acc = 0.0f;
    float sf = -CENTER;
    #pragma unroll 4
    for (int si = 0; si < N_IMG; ++si) {
        float X = fmaf(sf, -sn, Xb);
        float Y = fmaf(sf,  cs, Yb);
        float fx = floorf(X), fy = floorf(Y);
        float wx = X - fx,  wy = Y - fy;
        int cp = (int)fx + 1;         // padded col index of left tap
        int rp = (int)fy + 1;         // padded row index of top tap
        // contributes iff floor in [-1,255] on both axes -> padded idx in [0,256]
        bool ok = ((unsigned)rp <= 256u) && ((unsigned)cp <= 256u);
        int hidx = ok ? (rp * PADW + cp) : (257 * PADW);   // dump: all-zero taps
        const __half* p0 = &S[hidx];
        float v00 = __half2float(p0[0]);
        float v01 = __half2float(p0[1]);
        float v10 = __half2float(p0[PADW]);
        float v11 = __half2float(p0[PADW + 1]);
        float a0 = fmaf(wy, v10 - v00, v00);
        float a1 = fmaf(wy, v11 - v01, v01);
        acc += fmaf(wx, a1 - a0, a0);
        sf += 1.0f;
    }
    out[((size_t)b * N_ANG + a) * N_IMG + d] = acc;
}

extern "C" void kernel_launch(void* const* d_in, const int* in_sizes, int n_in,
                              void* d_out, int out_size, void* d_ws, size_t ws_size,
                              hipStream_t stream) {
    const float* x      = (const float*)d_in[0];
    const float* angles = (const float*)d_in[1];
    float* out = (float*)d_out;
    // 512 blocks = 8 batches x 64 angle-groups; batch = blockIdx % 8 (XCD swizzle)
    radon_lds<<<N_BATCH * (N_ANG / 4), 1024, 0, stream>>>(x, angles, out);
}

// Round 3
// 224.910 us; speedup vs baseline: 2.5610x; 2.1294x over previous
//
#include <hip/hip_runtime.h>
#include <hip/hip_fp16.h>

#define N_IMG 256
#define N_ANG 256
#define N_BATCH 8
#define CENTER 127.5f
#define PADC 258                    // padded cols 0..257 (orig col = pc-1)
#define NPAIR 129                   // row-pairs k=0..128 covering padded rows 0..257
#define DUMP_IDX (NPAIR * PADC)     // 2 zero dwords for OOB redirect
#define LDS_DW (NPAIR * PADC + 2)   // 33,284 dwords = 133,136 B

// One block = one batch image staged to LDS as vertical fp16 row-pairs + 4 angles.
// Pair dword S[k*258+pc] = half2(padrow 2k, padrow 2k+1) at padded col pc.
// A bilinear sample reads 2x ds_read2_b32 (adjacent-dword pairs) instead of
// 4x ds_read_u16; row parity is resolved with a 0/16-bit shift before cvt.
__global__ __launch_bounds__(1024) void radon_pair(const float* __restrict__ x,
                                                   const float* __restrict__ angles,
                                                   float* __restrict__ out) {
    __shared__ uint32_t S[LDS_DW];

    int b    = blockIdx.x & 7;       // batch = blockIdx % 8 (XCD-resident image)
    int agrp = blockIdx.x >> 3;      // 0..63, 4 angles each
    int tid  = threadIdx.x;

    // ---- stage: build padded row-pair texture (writes every entry, no pre-zero)
    const float* im = x + (size_t)b * (N_IMG * N_IMG);
    for (int idx = tid; idx < NPAIR * PADC; idx += 1024) {
        int k  = idx / PADC;
        int pc = idx - k * PADC;
        int c  = pc - 1;             // orig col
        int rt = 2 * k - 1;          // padded row 2k   -> orig row 2k-1 (low half)
        int rb = 2 * k;              // padded row 2k+1 -> orig row 2k   (high half)
        bool cok = (unsigned)c < 256u;
        float top = (cok && (unsigned)rt < 256u) ? im[rt * 256 + c] : 0.0f;
        float bot = (cok && (unsigned)rb < 256u) ? im[rb * 256 + c] : 0.0f;
        uint32_t dw = (uint32_t)__half_as_ushort(__float2half(top))
                    | ((uint32_t)__half_as_ushort(__float2half(bot)) << 16);
        S[idx] = dw;
    }
    if (tid == 0) { S[DUMP_IDX] = 0u; S[DUMP_IDX + 1] = 0u; }
    __syncthreads();

    // ---- per-thread ray setup
    int d = tid & 255;               // detector
    int a = agrp * 4 + (tid >> 8);   // angle (wave-uniform: 4 waves per angle)
    float ang = angles[a];
    float sn = sinf(ang), cs = cosf(ang);
    float td = (float)d - CENTER;
    // Reference: X = t*cos - s*sin + c (col), Y = t*sin + s*cos + c (row)
    float Xb = fmaf(td, cs, CENTER);
    float Yb = fmaf(td, sn, CENTER);

    // ---- wave-uniform s-range clip: sample can contribute iff X,Y in [-1,256]
    float loY, hiY, loX, hiX;
    {   // Y = Yb + sf*cs  (cs wave-uniform -> uniform branch)
        if (fabsf(cs) > 1e-6f) {
            float r = 1.0f / cs;
            float p = (-1.0f - Yb) * r + CENTER;
            float q = (256.0f - Yb) * r + CENTER;
            loY = fminf(p, q); hiY = fmaxf(p, q);
        } else if (Yb >= -1.01f && Yb <= 256.01f) { loY = 0.f; hiY = 255.f; }
        else { loY = 1e9f; hiY = -1e9f; }
    }
    {   // X = Xb + sf*(-sn)
        if (fabsf(sn) > 1e-6f) {
            float r = -1.0f / sn;
            float p = (-1.0f - Xb) * r + CENTER;
            float q = (256.0f - Xb) * r + CENTER;
            loX = fminf(p, q); hiX = fmaxf(p, q);
        } else if (Xb >= -1.01f && Xb <= 256.01f) { loX = 0.f; hiX = 255.f; }
        else { loX = 1e9f; hiX = -1e9f; }
    }
    float lo = fmaxf(loY, loX), hi = fminf(hiY, hiX);
    int sLo = max(0, (int)ceilf(lo - 1e-3f));
    int sHi = min(255, (int)floorf(hi + 1e-3f));
    #pragma unroll
    for (int m = 1; m < 64; m <<= 1) {
        sLo = min(sLo, __shfl_xor(sLo, m, 64));
        sHi = max(sHi, __shfl_xor(sHi, m, 64));
    }

    // ---- main loop: 2x ds_read2_b32 per sample
    float acc = 0.0f;
    float sf = (float)sLo - CENTER;
    #pragma unroll 4
    for (int si = sLo; si <= sHi; ++si) {
        float X = fmaf(sf, -sn, Xb);
        float Y = fmaf(sf,  cs, Yb);
        float fx = floorf(X), fy = floorf(Y);
        float wx = X - fx,  wy = Y - fy;
        int cp = (int)fx + 1;        // padded col of left taps
        int pr = (int)fy + 1;        // padded row of top taps
        bool ok = ((unsigned)pr <= 256u) && ((unsigned)cp <= 256u);
        int par = pr & 1;
        int idxA = (pr >> 1) * PADC + cp;          // pair k0: contains row pr
        int idxB = idxA + (par ? PADC : 0);        // pair k1: contains row pr+1
        if (!ok) { idxA = DUMP_IDX; idxB = DUMP_IDX; }
        uint32_t A0 = S[idxA],  A1 = S[idxA + 1];  // -> ds_read2_b32
        uint32_t B0 = S[idxB],  B1 = S[idxB + 1];  // -> ds_read2_b32
        int shT = par << 4;          // component of row pr   in pair k0
        int shB = shT ^ 16;          // component of row pr+1 in pair k1
        float v00 = __half2float(__ushort_as_half((unsigned short)(A0 >> shT)));
        float v01 = __half2float(__ushort_as_half((unsigned short)(A1 >> shT)));
        float v10 = __half2float(__ushort_as_half((unsigned short)(B0 >> shB)));
        float v11 = __half2float(__ushort_as_half((unsigned short)(B1 >> shB)));
        float a0 = fmaf(wy, v10 - v00, v00);
        float a1 = fmaf(wy, v11 - v01, v01);
        acc += fmaf(wx, a1 - a0, a0);
        sf += 1.0f;
    }
    out[((size_t)b * N_ANG + a) * N_IMG + d] = acc;
}

extern "C" void kernel_launch(void* const* d_in, const int* in_sizes, int n_in,
                              void* d_out, int out_size, void* d_ws, size_t ws_size,
                              hipStream_t stream) {
    const float* x      = (const float*)d_in[0];
    const float* angles = (const float*)d_in[1];
    float* out = (float*)d_out;
    radon_pair<<<N_BATCH * (N_ANG / 4), 1024, 0, stream>>>(x, angles, out);
}

// Round 4
// 184.459 us; speedup vs baseline: 3.1226x; 1.2193x over previous
//
#include <hip/hip_runtime.h>
#include <hip/hip_fp16.h>

#define N_IMG 256
#define N_ANG 256
#define N_BATCH 8
#define PADC 258                     // padded cols 0..257 (orig col = pc-1)
#define NE_MAX 129                   // max row-entries per half
#define DUMP_IDX (NE_MAX * PADC)     // 2 zero dwords for OOB redirect
#define LDS_DW (DUMP_IDX + 2)        // 33,284 dwords = 133,136 B

// Overlapping-pair texture, half-image per block:
//   T[e][pc] = half2( img[prLo+e-1][pc-1], img[prLo+e][pc-1] )   (0 outside)
// A bilinear sample with padded-row pr = floor(Y)+1 and padded-col cp =
// floor(X)+1 reads ONE ds_read2_b32 at (e=pr-prLo, cp),(e,cp+1): dword lo
// half = top tap, hi half = bottom tap. Two blocks (h=0: pr 0..128,
// h=1: pr 129..256) accumulate partial ray sums via atomicAdd.
__global__ __launch_bounds__(1024) void radon_ovl(const float* __restrict__ x,
                                                  const float* __restrict__ angles,
                                                  float* __restrict__ out) {
    __shared__ uint32_t S[LDS_DW];

    int bid  = blockIdx.x;
    int b    = bid & 7;              // batch (XCD-resident image)
    int rest = bid >> 3;
    int agrp = rest & 63;            // 4 angles per block
    int h    = rest >> 6;            // image half
    int prLo = h ? 129 : 0;
    int nE   = h ? 128 : 129;
    int tid  = threadIdx.x;

    // ---- stage overlapping row-pair texture for this half
    const float* im = x + (size_t)b * (N_IMG * N_IMG);
    for (int idx = tid; idx < nE * PADC; idx += 1024) {
        int e  = idx / PADC;
        int pc = idx - e * PADC;
        int c  = pc - 1;
        int rT = prLo + e - 1;       // top tap row (orig)
        int rB = rT + 1;             // bottom tap row
        bool cok = (unsigned)c < 256u;
        float vT = (cok && (unsigned)rT < 256u) ? im[rT * 256 + c] : 0.0f;
        float vB = (cok && (unsigned)rB < 256u) ? im[rB * 256 + c] : 0.0f;
        __half2 hv = __floats2half2_rn(vT, vB);
        S[idx] = *reinterpret_cast<uint32_t*>(&hv);
    }
    if (tid < 2) S[DUMP_IDX + tid] = 0u;
    __syncthreads();

    // ---- per-thread ray setup (4 waves per angle; wave = 64 consecutive d)
    int d = tid & 255;
    int a = agrp * 4 + (tid >> 8);
    float ang = angles[a];
    float sn = sinf(ang), cs = cosf(ang);
    float td = (float)d - 127.5f;
    // Global padded coords (identical arithmetic in both h-blocks!):
    //   X2 = Xb2 - sf*sn  (cp = floor(X2), valid [0,256])
    //   Y2 = Yb2 + sf*cs  (pr = floor(Y2), valid [0,256]; block owns pr-prLo in [0,nE))
    float Xb2 = fmaf(td, cs, 128.5f);
    float Yb2 = fmaf(td, sn, 128.5f);

    // per-lane sf window (loose by ±0.2 + integer margin; ok-test is authoritative)
    float lo = -127.5f, hi = 127.5f;
    float prL = (float)prLo, prH = (float)(prLo + nE);
    if (fabsf(cs) > 1e-6f) {
        float r = 1.0f / cs;
        float p = (prL - 0.2f - Yb2) * r;
        float q = (prH + 0.2f - Yb2) * r;
        lo = fmaxf(lo, fminf(p, q)); hi = fminf(hi, fmaxf(p, q));
    } else if (!(Yb2 > prL - 0.2f && Yb2 < prH + 0.2f)) { lo = 1.0f; hi = 0.0f; }
    if (fabsf(sn) > 1e-6f) {
        float r = -1.0f / sn;
        float p = (-0.2f - Xb2) * r;
        float q = (257.2f - Xb2) * r;
        lo = fmaxf(lo, fminf(p, q)); hi = fminf(hi, fmaxf(p, q));
    } else if (!(Xb2 > -0.2f && Xb2 < 257.2f)) { lo = 1.0f; hi = 0.0f; }
    int siLo = max(0,   (int)ceilf(lo + 127.5f) - 1);
    int siHi = min(255, (int)floorf(hi + 127.5f) + 1);

    // ---- main loop: 1x ds_read2_b32 + packed-fp16 vertical lerp per sample
    float acc = 0.0f;
    float sf = (float)siLo - 127.5f;
    #pragma unroll 4
    for (int si = siLo; si <= siHi; ++si) {
        float X2 = fmaf(sf, -sn, Xb2);
        float Y2 = fmaf(sf,  cs, Yb2);
        float fx = floorf(X2), fy = floorf(Y2);
        float wx = X2 - fx, wy = Y2 - fy;
        int cp = (int)fx;
        int e  = (int)fy - prLo;     // integer sub -> exact h-partition
        bool ok = ((unsigned)e < (unsigned)nE) & ((unsigned)cp < 257u);
        int idx = ok ? (e * PADC + cp) : DUMP_IDX;
        uint32_t A0 = S[idx], A1 = S[idx + 1];                    // ds_read2_b32
        uint32_t Pu = __builtin_amdgcn_perm(A1, A0, 0x05040100u); // (topL, topR)
        uint32_t Qu = __builtin_amdgcn_perm(A1, A0, 0x07060302u); // (botL, botR)
        __half2 Ph = *reinterpret_cast<__half2*>(&Pu);
        __half2 Qh = *reinterpret_cast<__half2*>(&Qu);
        __half2 wy2 = __float2half2_rn(wy);
        __half2 Rh = __hfma2(wy2, __hsub2(Qh, Ph), Ph);           // vertical lerp
        float r0 = __low2float(Rh), r1 = __high2float(Rh);
        acc += fmaf(wx, r1 - r0, r0);                             // horizontal lerp
        sf += 1.0f;
    }
    unsafeAtomicAdd(&out[((size_t)b * N_ANG + a) * N_IMG + d], acc);
}

extern "C" void kernel_launch(void* const* d_in, const int* in_sizes, int n_in,
                              void* d_out, int out_size, void* d_ws, size_t ws_size,
                              hipStream_t stream) {
    const float* x      = (const float*)d_in[0];
    const float* angles = (const float*)d_in[1];
    float* out = (float*)d_out;
    hipMemsetAsync(out, 0, (size_t)out_size * sizeof(float), stream);
    // 1024 blocks = 8 batches x 64 angle-groups x 2 halves; batch = blockIdx%8
    radon_ovl<<<N_BATCH * (N_ANG / 4) * 2, 1024, 0, stream>>>(x, angles, out);
}

// Round 5
// 172.910 us; speedup vs baseline: 3.3311x; 1.0668x over previous
//
#include <hip/hip_runtime.h>
#include <hip/hip_fp16.h>

#define N_IMG 256
#define N_ANG 256
#define N_BATCH 8
#define STRIDE 261                  // dword row stride (260 cols used + 1 pad)
#define MAXROWS 67                  // nE+2 <= 67

#if defined(__has_builtin)
#  if __has_builtin(__builtin_amdgcn_fdot2)
#    define HAVE_FDOT2 1
#  endif
#endif

// Quarter-image overlapping-pair texture (2 blocks/CU):
//   row t (1..nE):  T[t][u] = half2( img[prLo+t-2][u-2], img[prLo+t-1][u-2] ), 0 outside
//   rows t=0 and t=nE+1: ZERO  -> exact pr-partition without per-sample bounds test
// Sample with pr=floor(Yp), cp=floor(Xp): one ds_read2_b32 at
// idx=(pr-prLo+1)*261 + cp+1 gives all 4 taps (lo16=top, hi16=bottom).
// 4 quarter-blocks accumulate each ray via atomicAdd; windows are float
// crossings with 0.9 margin (slack rows/cols absorb the +-0.1 float error).
__global__ __launch_bounds__(1024, 8) void radon_q(const float* __restrict__ x,
                                                   const float* __restrict__ angles,
                                                   float* __restrict__ out) {
    __shared__ uint32_t S[MAXROWS * STRIDE];   // 17,487 dw = 69,948 B

    int bid  = blockIdx.x;
    int b    = bid & 7;              // batch (XCD-resident image)
    int rest = bid >> 3;
    int agrp = rest & 63;            // 4 angles per block
    int qq   = rest >> 6;            // quarter 0..3
    int prLo = (qq == 0) ? 0 : (qq * 64 + 1);   // owns pr in [prLo, prLo+nE-1]
    int nE   = (qq == 0) ? 65 : 64;
    int tid  = threadIdx.x;

    // ---- stage texture
    const float* im = x + (size_t)b * (N_IMG * N_IMG);
    int nEnt = (nE + 2) * STRIDE;
    for (int idx = tid; idx < nEnt; idx += 1024) {
        int t = idx / STRIDE;
        int u = idx - t * STRIDE;
        int c = u - 2;
        int rT = prLo + t - 2, rB = rT + 1;
        bool real = (t >= 1) & (t <= nE) & ((unsigned)c < 256u);
        float vT = (real && (unsigned)rT < 256u) ? im[rT * 256 + c] : 0.0f;
        float vB = (real && (unsigned)rB < 256u) ? im[rB * 256 + c] : 0.0f;
        __half2 hv = __floats2half2_rn(vT, vB);
        S[idx] = *reinterpret_cast<const uint32_t*>(&hv);
    }
    __syncthreads();

    // ---- ray setup: Xp = Xb - sf*sn, Yp = Yb + sf*cs  (padded coords = ref+1)
    int d = tid & 255;
    int a = agrp * 4 + (tid >> 8);
    float ang = angles[a];
    float sn = sinf(ang), cs = cosf(ang);
    float td = (float)d - 127.5f;
    float Xb = fmaf(td, cs, 128.5f);
    float Yb = fmaf(td, sn, 128.5f);

    // per-lane sf window with 0.9-margin crossings
    float lo = -127.5f, hi = 127.5f;
    float yL = (float)prLo - 0.9f, yH = (float)(prLo + nE) + 0.9f;
    if (fabsf(cs) > 1e-6f) {
        float r = 1.0f / cs;
        float p = (yL - Yb) * r, q2 = (yH - Yb) * r;
        lo = fmaxf(lo, fminf(p, q2)); hi = fminf(hi, fmaxf(p, q2));
    } else if (!(Yb > yL + 0.4f && Yb < yH - 0.4f)) { lo = 1.0f; hi = 0.0f; }
    if (fabsf(sn) > 1e-6f) {
        float r = -1.0f / sn;
        float p = (-0.9f - Xb) * r, q2 = (257.9f - Xb) * r;
        lo = fmaxf(lo, fminf(p, q2)); hi = fminf(hi, fmaxf(p, q2));
    } else if (!(Xb > -0.4f && Xb < 257.4f)) { lo = 1.0f; hi = 0.0f; }
    int siLo = max(0,   (int)ceilf(lo + 127.5f));
    int siHi = min(255, (int)floorf(hi + 127.5f));

    // idx = pr*261 + cp + KOFF   (KOFF folds the (pr-prLo+1, cp+1) shifts)
    int KOFF = (1 - prLo) * STRIDE + 1;

    // ---- main loop: 1 ds_read2_b32 + ~19 VALU per sample, no bounds test
    float acc = 0.0f;
    float sf = (float)siLo - 127.5f;
    #pragma unroll 4
    for (int si = siLo; si <= siHi; ++si) {
        float Xp = fmaf(sf, -sn, Xb);
        float Yp = fmaf(sf,  cs, Yb);
        float fx = floorf(Xp), fy = floorf(Yp);
        float wx = Xp - fx, wy = Yp - fy;
        int cp = (int)fx, pr = (int)fy;
        int idx = pr * STRIDE + cp + KOFF;
        uint32_t A0 = S[idx], A1 = S[idx + 1];                     // ds_read2_b32
        uint32_t Pu = __builtin_amdgcn_perm(A1, A0, 0x05040100u);  // (topL, topR)
        uint32_t Qu = __builtin_amdgcn_perm(A1, A0, 0x07060302u);  // (botL, botR)
        __half2 Ph = *reinterpret_cast<__half2*>(&Pu);
        __half2 Qh = *reinterpret_cast<__half2*>(&Qu);
        __half2 wy2 = __float2half2_rn(wy);
        __half2 Rh = __hfma2(wy2, __hsub2(Qh, Ph), Ph);            // vertical lerp
#ifdef HAVE_FDOT2
        __half2 W = __floats2half2_rn(1.0f - wx, wx);
        acc = __builtin_amdgcn_fdot2(Rh, W, acc, false);           // horizontal lerp
#else
        float r0 = __low2float(Rh), r1 = __high2float(Rh);
        acc += fmaf(wx, r1 - r0, r0);
#endif
        sf += 1.0f;
    }
    unsafeAtomicAdd(&out[((size_t)b * N_ANG + a) * N_IMG + d], acc);
}

extern "C" void kernel_launch(void* const* d_in, const int* in_sizes, int n_in,
                              void* d_out, int out_size, void* d_ws, size_t ws_size,
                              hipStream_t stream) {
    const float* x      = (const float*)d_in[0];
    const float* angles = (const float*)d_in[1];
    float* out = (float*)d_out;
    hipMemsetAsync(out, 0, (size_t)out_size * sizeof(float), stream);
    // 2048 blocks = 8 batches x 64 angle-groups x 4 quarters; batch = blockIdx%8
    radon_q<<<N_BATCH * (N_ANG / 4) * 4, 1024, 0, stream>>>(x, angles, out);
}